// Round 8
// baseline (2694.473 us; speedup 1.0000x reference)
//
#include <hip/hip_runtime.h>
#include <hip/hip_bf16.h>

#define TT 1024
#define DD 768
#define HH 12
#define LL 12
#define VV 50257
#define MROWS 2048   // B*T

typedef __attribute__((ext_vector_type(4))) float f32x4;
typedef __attribute__((ext_vector_type(8))) short bf16x8;

__device__ __forceinline__ short f2bf(float f) {
  __hip_bfloat16 h = __float2bfloat16(f);
  short s;
  __builtin_memcpy(&s, &h, 2);
  return s;
}

__device__ __forceinline__ void gload16(const void* g, void* l) {
  __builtin_amdgcn_global_load_lds(
      (const __attribute__((address_space(1))) unsigned int*)g,
      (__attribute__((address_space(3))) unsigned int*)l, 16, 0, 0);
}

__device__ __forceinline__ float wsum(float v) {
#pragma unroll
  for (int o = 32; o; o >>= 1) v += __shfl_xor(v, o, 64);
  return v;
}

// ---------------- fp32 -> bf16 weight conversion ----------------
__global__ __launch_bounds__(256) void cvt_k(const float* __restrict__ src,
                                             short* __restrict__ dst, long n4)
{
  const long stride = (long)gridDim.x * 256;
  for (long i = (long)blockIdx.x * 256 + threadIdx.x; i < n4; i += stride) {
    const float4 v = ((const float4*)src)[i];
    short4 h;
    h.x = f2bf(v.x); h.y = f2bf(v.y); h.z = f2bf(v.z); h.w = f2bf(v.w);
    ((short4*)dst)[i] = h;
  }
}

// ---------------- embedding ----------------
__global__ __launch_bounds__(256) void embed_k(const int* __restrict__ idx,
    const float* __restrict__ tok, const float* __restrict__ pos,
    float* __restrict__ x)
{
  int i = blockIdx.x * 256 + threadIdx.x;
  int d = i % DD;
  int bt = i / DD;
  int t = bt & (TT - 1);
  x[i] = tok[(long)idx[bt] * DD + d] + pos[t * DD + d];
}

// ---------------- LayerNorm (fp32 in) -> bf16 out ----------------
__global__ __launch_bounds__(256) void ln_k(const float* __restrict__ x,
    const float* __restrict__ g, const float* __restrict__ b,
    short* __restrict__ out)
{
  const int row = blockIdx.x;
  const float* xr = x + (long)row * DD;
  float vals[3];
  float s = 0.f, s2 = 0.f;
#pragma unroll
  for (int i = 0; i < 3; ++i) {
    float v = xr[threadIdx.x + i * 256];
    vals[i] = v; s += v; s2 += v * v;
  }
  __shared__ float rs[4], rs2[4];
  s = wsum(s); s2 = wsum(s2);
  if (!(threadIdx.x & 63)) { rs[threadIdx.x >> 6] = s; rs2[threadIdx.x >> 6] = s2; }
  __syncthreads();
  s  = rs[0] + rs[1] + rs[2] + rs[3];
  s2 = rs2[0] + rs2[1] + rs2[2] + rs2[3];
  const float mu = s * (1.f / DD);
  const float var = s2 * (1.f / DD) - mu * mu;
  const float rstd = rsqrtf(var + 1e-5f);
#pragma unroll
  for (int i = 0; i < 3; ++i) {
    int d = threadIdx.x + i * 256;
    out[(long)row * DD + d] = f2bf((vals[i] - mu) * rstd * g[d] + b[d]);
  }
}

// ---------------- V transpose: vt[z][d][t] ----------------
__global__ __launch_bounds__(256) void vtrans_k(const short* __restrict__ qkv,
                                                short* __restrict__ vt)
{
  const int tt = blockIdx.x;   // t-chunk of 64
  const int z  = blockIdx.y;   // b*H + h
  const int zb = z / HH, zh = z % HH;
  __shared__ short tile[64][65];
  for (int e = threadIdx.x; e < 64 * 64; e += 256) {
    int lt = e >> 6, d = e & 63;
    tile[lt][d] = qkv[(long)(zb * TT + tt * 64 + lt) * (3 * DD) + 2 * DD + zh * 64 + d];
  }
  __syncthreads();
  for (int e = threadIdx.x; e < 64 * 64; e += 256) {
    int d = e >> 6, lt = e & 63;
    vt[((long)z * 64 + d) * TT + tt * 64 + lt] = tile[lt][d];
  }
}

// ---------------- flash attention, 4-way kv-split ----------------
__global__ __launch_bounds__(256) void flash_k(const short* __restrict__ qkv,
                                               const short* __restrict__ vt,
                                               short* __restrict__ y)
{
  const int qt = (int)gridDim.x - 1 - (int)blockIdx.x;  // longest blocks first
  const int z  = blockIdx.y;
  const int zb = z / HH, zh = z % HH;
  const int w    = threadIdx.x >> 6;
  const int lane = threadIdx.x & 63;
  const int c = lane & 15, g = lane >> 4;

  __shared__ short Pl[4][16][40];
  __shared__ float Ol[4][16][64];
  __shared__ float ml[4][16], ll[4][16];

  const int qbase = qt * 16;
  const long rowQ = (long)(zb * TT + qbase + c) * (3 * DD) + zh * 64;

  bf16x8 qf[2];
  qf[0] = *(const bf16x8*)(qkv + rowQ + g * 8);
  qf[1] = *(const bf16x8*)(qkv + rowQ + 32 + g * 8);

  f32x4 O[4] = {};
  f32x4 mrun, lrun;
#pragma unroll
  for (int r = 0; r < 4; ++r) { mrun[r] = -1e30f; lrun[r] = 0.f; }

  const float CSC = 0.125f * 1.44269504089f;
  const int nt = (qbase + 15) / 32 + 1;

  for (int t = w; t < nt; t += 4) {
    const int k0 = t * 32;
    f32x4 acc[2] = {};
#pragma unroll
    for (int nf = 0; nf < 2; ++nf) {
      const long rowK = (long)(zb * TT + k0 + nf * 16 + c) * (3 * DD) + DD + zh * 64;
      bf16x8 kf0 = *(const bf16x8*)(qkv + rowK + g * 8);
      bf16x8 kf1 = *(const bf16x8*)(qkv + rowK + 32 + g * 8);
      acc[nf] = __builtin_amdgcn_mfma_f32_16x16x32_bf16(qf[0], kf0, acc[nf], 0, 0, 0);
      acc[nf] = __builtin_amdgcn_mfma_f32_16x16x32_bf16(qf[1], kf1, acc[nf], 0, 0, 0);
    }
    f32x4 tv[2];
    const int mask_needed = (k0 + 31 > qbase);
#pragma unroll
    for (int nf = 0; nf < 2; ++nf) {
      const int k_abs = k0 + nf * 16 + c;
#pragma unroll
      for (int r = 0; r < 4; ++r) {
        float val = acc[nf][r] * CSC;
        if (mask_needed && k_abs > qbase + g * 4 + r) val = -1e30f;
        tv[nf][r] = val;
      }
    }
    f32x4 rmax;
#pragma unroll
    for (int r = 0; r < 4; ++r) rmax[r] = fmaxf(tv[0][r], tv[1][r]);
#pragma unroll
    for (int off = 1; off < 16; off <<= 1) {
#pragma unroll
      for (int r = 0; r < 4; ++r) rmax[r] = fmaxf(rmax[r], __shfl_xor(rmax[r], off, 64));
    }
    f32x4 mnew, rfac;
#pragma unroll
    for (int r = 0; r < 4; ++r) {
      mnew[r] = fmaxf(mrun[r], rmax[r]);
      rfac[r] = exp2f(mrun[r] - mnew[r]);
      mrun[r] = mnew[r];
    }
    f32x4 e0, e1, rsum;
#pragma unroll
    for (int r = 0; r < 4; ++r) {
      e0[r] = exp2f(tv[0][r] - mnew[r]);
      e1[r] = exp2f(tv[1][r] - mnew[r]);
      rsum[r] = e0[r] + e1[r];
    }
#pragma unroll
    for (int off = 1; off < 16; off <<= 1) {
#pragma unroll
      for (int r = 0; r < 4; ++r) rsum[r] += __shfl_xor(rsum[r], off, 64);
    }
#pragma unroll
    for (int r = 0; r < 4; ++r) lrun[r] = lrun[r] * rfac[r] + rsum[r];
#pragma unroll
    for (int nf = 0; nf < 4; ++nf)
#pragma unroll
      for (int r = 0; r < 4; ++r) O[nf][r] *= rfac[r];
#pragma unroll
    for (int r = 0; r < 4; ++r) {
      Pl[w][g * 4 + r][c]      = f2bf(e0[r]);
      Pl[w][g * 4 + r][16 + c] = f2bf(e1[r]);
    }
    asm volatile("s_waitcnt lgkmcnt(0)" ::: "memory");
    const bf16x8 pf = *(const bf16x8*)&Pl[w][c][g * 8];
#pragma unroll
    for (int nf = 0; nf < 4; ++nf) {
      const bf16x8 vf = *(const bf16x8*)(vt + ((long)z * 64 + nf * 16 + c) * TT + k0 + g * 8);
      O[nf] = __builtin_amdgcn_mfma_f32_16x16x32_bf16(pf, vf, O[nf], 0, 0, 0);
    }
  }

  // ---- publish partials ----
#pragma unroll
  for (int nf = 0; nf < 4; ++nf)
#pragma unroll
    for (int r = 0; r < 4; ++r)
      Ol[w][g * 4 + r][nf * 16 + c] = O[nf][r];
  if (c == 0) {
#pragma unroll
    for (int r = 0; r < 4; ++r) { ml[w][g * 4 + r] = mrun[r]; ll[w][g * 4 + r] = lrun[r]; }
  }
  __syncthreads();

  // ---- merge 4 partials + normalize + write ----
  for (int e = threadIdx.x; e < 16 * 64; e += 256) {
    const int row = e >> 6, d = e & 63;
    const float M = fmaxf(fmaxf(ml[0][row], ml[1][row]), fmaxf(ml[2][row], ml[3][row]));
    float L = 0.f, Ov = 0.f;
#pragma unroll
    for (int u = 0; u < 4; ++u) {
      const float f = exp2f(ml[u][row] - M);
      L += ll[u][row] * f;
      Ov += Ol[u][row][d] * f;
    }
    y[(long)(zb * TT + qbase + row) * DD + zh * 64 + d] = f2bf(Ov / L);
  }
}

// ---------------- NT GEMM: C[m,n] = sum_k A[m,k] * B[n,k]  (+ epilogue) ----------------
// MREP: per-block M-repeat — one B-tile in LDS feeds MREP A-tiles (raises
// MFMA-per-LDS-byte ratio, the r7 diagnosed bound). PIPE: 2-phase dbuf with
// counted vmcnt for the ~1 block/CU layer regime; single-buffer for the
// self-pipelining LM head. XOR chunk swizzle on global SOURCE + reads (r5).
// EPI: 0 fp32*scale ; 1 bf16+bias ; 2 fp32 resid+acc+bias ; 3 bf16 gelu ; 4 bf16 plain
template<int BM, int BN, int BK, int MREP, typename TB, int EPI, bool LMSWZ, bool PIPE>
__global__ __launch_bounds__(256) void gemm_nt(
    const short* __restrict__ A, const TB* __restrict__ Bm,
    const float* __restrict__ bias, const float* __restrict__ resid,
    void* __restrict__ Cout,
    int M, int N, int K, int lda, int ldb, int ldc,
    long aSB, long aSH, long bSB, long bSH, long cSB, long cSH,
    float scale, int causal)
{
  int n0, m0;
  if constexpr (LMSWZ) {
    // bijective XCD-pinned n-panels; m-tiles = M/(BM*MREP) = 8 (M=2048,BM=128,MREP=2)
    const int l = blockIdx.x;
    const int x = l & 7;
    const int j = l >> 3;
    const int mt = j & 7;
    const int nl = j >> 3;
    const int npan = (N + BN - 1) / BN;
    const int q = npan >> 3, rr = npan & 7;
    const int cnt = q + (x < rr);
    if (nl >= cnt) return;
    const int nstart = x * q + (x < rr ? x : rr);
    n0 = (nstart + nl) * BN;
    m0 = mt * (BM * MREP);
  } else {
    n0 = blockIdx.x * BN;
    m0 = blockIdx.y * (BM * MREP);
  }
  if (causal && n0 >= m0 + BM * MREP) return;
  const int z = blockIdx.z;
  const int zb = z / HH, zh = z % HH;
  const short* Ag = A + zb * aSB + zh * aSH + (long)m0 * lda;
  const TB*    Bg = Bm + zb * bSB + zh * bSH;
  const long  cOff = zb * cSB + zh * cSH;

  constexpr int NBUF = PIPE ? 2 : 1;
  constexpr int AR = BM * MREP;          // A rows staged
  __shared__ __align__(16) short Als[NBUF][AR][BK];
  __shared__ __align__(16) short Bls[NBUF][BN][BK];

  const int tid = threadIdx.x;
  const int lane = tid & 63, wid = tid >> 6;
  constexpr int WTM = BM / 2, WTN = BN / 2;
  constexpr int FM = WTM / 16, FN = WTN / 16;
  const int wr = wid >> 1, wc = wid & 1;

  f32x4 acc[MREP][FM][FN] = {};
  const int kAoff = (lane >> 4) * 8;
  constexpr bool B_IS_F32 = (sizeof(TB) == 4);
  constexpr int CPR = BK / 8;            // 16B chunks per row
  constexpr int NCA = AR * CPR;
  constexpr int NCB = BN * CPR;
  constexpr int IA = NCA / 256, IB = NCB / 256;
  constexpr int GPT = IA + IB;           // gloads per thread per tile
  static_assert(CPR == 8, "swizzle assumes 128B rows (BK=64)");
  static_assert(B_IS_F32 || (NCA % 256 == 0 && NCB % 256 == 0), "chunk grid");

  // fragment compute over buffer `buf`
  auto compute = [&](int buf) {
#pragma unroll
    for (int kk = 0; kk < BK; kk += 32) {
      const int kc = (kk + kAoff) >> 3;
      bf16x8 bfr[FN];
#pragma unroll
      for (int ni = 0; ni < FN; ++ni) {
        const int Rb = wc * WTN + ni * 16 + (lane & 15);
        bfr[ni] = *(const bf16x8*)&Bls[buf][Rb][(kc ^ (Rb & 7)) << 3];
      }
#pragma unroll
      for (int mp = 0; mp < MREP; ++mp) {
        bf16x8 af[FM];
#pragma unroll
        for (int mi = 0; mi < FM; ++mi) {
          const int Ra = mp * BM + wr * WTM + mi * 16 + (lane & 15);
          af[mi] = *(const bf16x8*)&Als[buf][Ra][(kc ^ (Ra & 7)) << 3];
        }
#pragma unroll
        for (int mi = 0; mi < FM; ++mi)
#pragma unroll
          for (int ni = 0; ni < FN; ++ni)
            acc[mp][mi][ni] = __builtin_amdgcn_mfma_f32_16x16x32_bf16(af[mi], bfr[ni], acc[mp][mi][ni], 0, 0, 0);
      }
    }
  };

  if constexpr (!B_IS_F32) {
    const short* ap[IA];
    const short* bp[IB];
#pragma unroll
    for (int i = 0; i < IA; ++i) {
      const int cch = i * 256 + tid;
      const int r = cch / CPR, kc = cch % CPR;
      ap[i] = Ag + (long)r * lda + ((kc ^ (r & 7)) << 3);
    }
#pragma unroll
    for (int i = 0; i < IB; ++i) {
      const int cch = i * 256 + tid;
      const int r = cch / CPR, kc = cch % CPR;
      int gr = n0 + r; gr = (gr < N) ? gr : (N - 1);
      bp[i] = (const short*)Bg + (long)gr * ldb + ((kc ^ (r & 7)) << 3);
    }
    const int ldsoff = wid * 64 * 16;    // wave-uniform base; HW adds lane*16

    auto stage = [&](int buf) {
#pragma unroll
      for (int i = 0; i < IA; ++i) {
        gload16(ap[i], (char*)&Als[buf][0][0] + i * 4096 + ldsoff);
        ap[i] += BK;
      }
#pragma unroll
      for (int i = 0; i < IB; ++i) {
        gload16(bp[i], (char*)&Bls[buf][0][0] + i * 4096 + ldsoff);
        bp[i] += BK;
      }
    };

    if constexpr (PIPE) {
      const int KT = K / BK;
      stage(0);
      for (int kt = 0; kt < KT; ++kt) {
        const int cur = kt & 1;
        if (kt + 1 < KT) {
          stage(cur ^ 1);
          asm volatile("s_waitcnt vmcnt(%0)" :: "i"(GPT));
        } else {
          asm volatile("s_waitcnt vmcnt(0)");
        }
        __builtin_amdgcn_sched_barrier(0);
        __builtin_amdgcn_s_barrier();
        __builtin_amdgcn_sched_barrier(0);
        compute(cur);
        asm volatile("" ::: "memory");
        __builtin_amdgcn_s_barrier();
        __builtin_amdgcn_sched_barrier(0);
      }
    } else {
      const int KT = K / BK;
      for (int kt = 0; kt < KT; ++kt) {
        stage(0);
        __syncthreads();
        compute(0);
        __syncthreads();
      }
    }
  } else {
    // --- fp32 fallback: synchronous single-buffer staging with on-the-fly cvt ---
    for (int k0 = 0; k0 < K; k0 += BK) {
#pragma unroll
      for (int cc = tid; cc < NCA; cc += 256) {
        int r = cc / CPR, kc = cc % CPR;
        const uint4 v = *(const uint4*)(Ag + (long)r * lda + k0 + kc * 8);
        *(uint4*)((char*)&Als[0][r][0] + ((kc ^ (r & 7)) << 4)) = v;
      }
#pragma unroll
      for (int cc = tid; cc < BN * (BK / 4); cc += 256) {
        int r = cc / (BK / 4), kc = cc % (BK / 4);
        int gr = n0 + r; gr = (gr < N) ? gr : (N - 1);
        const float4 v = *(const float4*)((const float*)Bg + (long)gr * ldb + k0 + kc * 4);
        short4 h4;
        h4.x = f2bf(v.x); h4.y = f2bf(v.y); h4.z = f2bf(v.z); h4.w = f2bf(v.w);
        *(short4*)((char*)&Bls[0][r][0] + ((kc * 8) ^ ((r & 7) << 4))) = h4;
      }
      __syncthreads();
      compute(0);
      __syncthreads();
    }
  }

  const int rq = (lane >> 4) << 2;
  const int cl = lane & 15;
#pragma unroll
  for (int mp = 0; mp < MREP; ++mp) {
#pragma unroll
    for (int mi = 0; mi < FM; ++mi) {
#pragma unroll
      for (int ni = 0; ni < FN; ++ni) {
        const int cg = n0 + wc * WTN + ni * 16 + cl;
        if (cg >= N) continue;
        const int rbase = m0 + mp * BM + wr * WTM + mi * 16 + rq;
#pragma unroll
        for (int q = 0; q < 4; ++q) {
          const long cidx = cOff + (long)(rbase + q) * ldc + cg;
          const float v = acc[mp][mi][ni][q];
          if constexpr (EPI == 0) {
            ((float*)Cout)[cidx] = v * scale;
          } else if constexpr (EPI == 1) {
            ((short*)Cout)[cidx] = f2bf(v + bias[cg]);
          } else if constexpr (EPI == 2) {
            ((float*)Cout)[cidx] = resid[cidx] + v + bias[cg];
          } else if constexpr (EPI == 3) {
            const float zz = v + bias[cg];
            ((short*)Cout)[cidx] = f2bf(0.5f * zz * (1.f + erff(zz * 0.70710678118f)));
          } else {
            ((short*)Cout)[cidx] = f2bf(v);
          }
        }
      }
    }
  }
}

// ---------------- model driver ----------------
template<typename TB>
static void run_model(const int* idx, const float* tok_f, const float* pos,
                      const TB* wqkv, const float* bqkv, const TB* wproj, const float* bproj,
                      const float* ln1g, const float* ln1b, const float* ln2g, const float* ln2b,
                      const TB* w1, const float* b1, const TB* w2, const float* b2,
                      const float* lnfg, const float* lnfb, const TB* tok_w,
                      float* xa, float* xb, short* hbf, short* qkv, short* vt,
                      short* ybf, short* ffb,
                      float* out, hipStream_t stream)
{
  embed_k<<<dim3(MROWS * DD / 256), 256, 0, stream>>>(idx, tok_f, pos, xa);

  float* xc = xa;
  float* xn = xb;
  for (int l = 0; l < LL; ++l) {
    ln_k<<<dim3(MROWS), 256, 0, stream>>>(xc, ln1g + l * DD, ln1b + l * DD, hbf);
    // qkv: 128x128 (wave tile 64x64, ratio 2.0), 288 blocks, dbuf pipe
    gemm_nt<128, 128, 64, 1, TB, 1, false, true><<<dim3(18, 16, 1), 256, 0, stream>>>(
        hbf, wqkv + (long)l * 3 * DD * DD, bqkv + l * 3 * DD, nullptr, qkv,
        MROWS, 3 * DD, DD, DD, DD, 3 * DD, 0, 0, 0, 0, 0, 0, 1.f, 0);
    vtrans_k<<<dim3(16, 24), 256, 0, stream>>>(qkv, vt);
    flash_k<<<dim3(64, 24), 256, 0, stream>>>(qkv, vt, ybf);
    // proj: 64x96 -> exactly 256 blocks (1/CU, zero tail)
    gemm_nt<64, 96, 64, 1, TB, 2, false, true><<<dim3(8, 32, 1), 256, 0, stream>>>(
        ybf, wproj + (long)l * DD * DD, bproj + l * DD, xc, xn,
        MROWS, DD, DD, DD, DD, DD, 0, 0, 0, 0, 0, 0, 1.f, 0);
    ln_k<<<dim3(MROWS), 256, 0, stream>>>(xn, ln2g + l * DD, ln2b + l * DD, hbf);
    // fc1: 128x128, 384 blocks
    gemm_nt<128, 128, 64, 1, TB, 3, false, true><<<dim3(24, 16, 1), 256, 0, stream>>>(
        hbf, w1 + (long)l * 4 * DD * DD, b1 + l * 4 * DD, nullptr, ffb,
        MROWS, 4 * DD, DD, DD, DD, 4 * DD, 0, 0, 0, 0, 0, 0, 1.f, 0);
    // fc2: 64x96, 256 blocks, K=3072 (48-deep pipe)
    gemm_nt<64, 96, 64, 1, TB, 2, false, true><<<dim3(8, 32, 1), 256, 0, stream>>>(
        ffb, w2 + (long)l * DD * 4 * DD, b2 + l * DD, xn, xc,
        MROWS, DD, 4 * DD, 4 * DD, 4 * DD, DD, 0, 0, 0, 0, 0, 0, 1.f, 0);
  }
  ln_k<<<dim3(MROWS), 256, 0, stream>>>(xc, lnfg, lnfb, hbf);
  // LM head: MREP=2 (one B-tile feeds 2 A-tiles, ratio 2.67), single-buffer,
  // 8 m-pairs x 393 n-panels XCD-pinned: 8*8*50 = 3200 blocks
  gemm_nt<128, 128, 64, 2, TB, 0, true, false><<<dim3(3200, 1, 1), 256, 0, stream>>>(
      hbf, tok_w, nullptr, nullptr, out,
      MROWS, VV, DD, DD, DD, VV, 0, 0, 0, 0, 0, 0, 1.f, 0);
}

extern "C" void kernel_launch(void* const* d_in, const int* in_sizes, int n_in,
                              void* d_out, int out_size, void* d_ws, size_t ws_size,
                              hipStream_t stream)
{
  const int*   idx  = (const int*)d_in[0];
  const float* tok  = (const float*)d_in[1];
  const float* pos  = (const float*)d_in[2];
  const float* wqkv = (const float*)d_in[3];
  const float* bqkv = (const float*)d_in[4];
  const float* wproj= (const float*)d_in[5];
  const float* bproj= (const float*)d_in[6];
  const float* ln1g = (const float*)d_in[7];
  const float* ln1b = (const float*)d_in[8];
  const float* ln2g = (const float*)d_in[9];
  const float* ln2b = (const float*)d_in[10];
  const float* w1   = (const float*)d_in[11];
  const float* b1   = (const float*)d_in[12];
  const float* w2   = (const float*)d_in[13];
  const float* b2   = (const float*)d_in[14];
  const float* lnfg = (const float*)d_in[15];
  const float* lnfb = (const float*)d_in[16];
  float* out = (float*)d_out;

  const long E_WQKV = (long)LL * 3 * DD * DD;
  const long E_WPRJ = (long)LL * DD * DD;
  const long E_W1   = (long)LL * 4 * DD * DD;
  const long E_W2   = E_W1;
  const long E_TOK  = (long)VV * DD;
  const long E_WSUM = E_WQKV + E_WPRJ + E_W1 + E_W2 + E_TOK;

  const size_t NEED_B = 44040192;
  const size_t NEED_A = NEED_B + 2 * (size_t)E_WSUM;

  if (ws_size < NEED_B) return;
  const bool bf16w = (ws_size >= NEED_A);

  char* ws = (char*)d_ws;
  short *wqkv_h = nullptr, *wprj_h = nullptr, *w1_h = nullptr, *w2_h = nullptr, *tok_h = nullptr;
  if (bf16w) {
    wqkv_h = (short*)ws; ws += E_WQKV * 2;
    wprj_h = (short*)ws; ws += E_WPRJ * 2;
    w1_h   = (short*)ws; ws += E_W1 * 2;
    w2_h   = (short*)ws; ws += E_W2 * 2;
    tok_h  = (short*)ws; ws += E_TOK * 2;
  }
  float* xa  = (float*)ws; ws += (size_t)MROWS * DD * 4;
  float* xb  = (float*)ws; ws += (size_t)MROWS * DD * 4;
  short* hbf = (short*)ws; ws += (size_t)MROWS * DD * 2;
  short* qkv = (short*)ws; ws += (size_t)MROWS * 3 * DD * 2;
  short* vt  = (short*)ws; ws += (size_t)24 * 64 * TT * 2;
  short* ybf = (short*)ws; ws += (size_t)MROWS * DD * 2;
  short* ffb = (short*)ws; ws += (size_t)MROWS * 4 * DD * 2;

  if (bf16w) {
    cvt_k<<<dim3(2048), 256, 0, stream>>>(wqkv, wqkv_h, E_WQKV / 4);
    cvt_k<<<dim3(2048), 256, 0, stream>>>(wproj, wprj_h, E_WPRJ / 4);
    cvt_k<<<dim3(2048), 256, 0, stream>>>(w1, w1_h, E_W1 / 4);
    cvt_k<<<dim3(2048), 256, 0, stream>>>(w2, w2_h, E_W2 / 4);
    cvt_k<<<dim3(2048), 256, 0, stream>>>(tok, tok_h, E_TOK / 4);
    run_model<short>(idx, tok, pos, wqkv_h, bqkv, wprj_h, bproj,
                     ln1g, ln1b, ln2g, ln2b, w1_h, b1, w2_h, b2, lnfg, lnfb, tok_h,
                     xa, xb, hbf, qkv, vt, ybf, ffb, out, stream);
  } else {
    run_model<float>(idx, tok, pos, wqkv, bqkv, wproj, bproj,
                     ln1g, ln1b, ln2g, ln2b, w1, b1, w2, b2, lnfg, lnfb, tok,
                     xa, xb, hbf, qkv, vt, ybf, ffb, out, stream);
  }
}

// Round 9
// 2515.303 us; speedup vs baseline: 1.0712x; 1.0712x over previous
//
#include <hip/hip_runtime.h>
#include <hip/hip_bf16.h>

#define TT 1024
#define DD 768
#define HH 12
#define LL 12
#define VV 50257
#define MROWS 2048   // B*T

typedef __attribute__((ext_vector_type(4))) float f32x4;
typedef __attribute__((ext_vector_type(8))) short bf16x8;

__device__ __forceinline__ short f2bf(float f) {
  __hip_bfloat16 h = __float2bfloat16(f);
  short s;
  __builtin_memcpy(&s, &h, 2);
  return s;
}

__device__ __forceinline__ void gload16(const void* g, void* l) {
  __builtin_amdgcn_global_load_lds(
      (const __attribute__((address_space(1))) unsigned int*)g,
      (__attribute__((address_space(3))) unsigned int*)l, 16, 0, 0);
}

__device__ __forceinline__ float wsum(float v) {
#pragma unroll
  for (int o = 32; o; o >>= 1) v += __shfl_xor(v, o, 64);
  return v;
}

// ---------------- fp32 -> bf16 weight conversion ----------------
__global__ __launch_bounds__(256) void cvt_k(const float* __restrict__ src,
                                             short* __restrict__ dst, long n4)
{
  const long stride = (long)gridDim.x * 256;
  for (long i = (long)blockIdx.x * 256 + threadIdx.x; i < n4; i += stride) {
    const float4 v = ((const float4*)src)[i];
    short4 h;
    h.x = f2bf(v.x); h.y = f2bf(v.y); h.z = f2bf(v.z); h.w = f2bf(v.w);
    ((short4*)dst)[i] = h;
  }
}

// ---------------- embedding ----------------
__global__ __launch_bounds__(256) void embed_k(const int* __restrict__ idx,
    const float* __restrict__ tok, const float* __restrict__ pos,
    float* __restrict__ x)
{
  int i = blockIdx.x * 256 + threadIdx.x;
  int d = i % DD;
  int bt = i / DD;
  int t = bt & (TT - 1);
  x[i] = tok[(long)idx[bt] * DD + d] + pos[t * DD + d];
}

// ---------------- LayerNorm (fp32 in) -> bf16 out ----------------
__global__ __launch_bounds__(256) void ln_k(const float* __restrict__ x,
    const float* __restrict__ g, const float* __restrict__ b,
    short* __restrict__ out)
{
  const int row = blockIdx.x;
  const float* xr = x + (long)row * DD;
  float vals[3];
  float s = 0.f, s2 = 0.f;
#pragma unroll
  for (int i = 0; i < 3; ++i) {
    float v = xr[threadIdx.x + i * 256];
    vals[i] = v; s += v; s2 += v * v;
  }
  __shared__ float rs[4], rs2[4];
  s = wsum(s); s2 = wsum(s2);
  if (!(threadIdx.x & 63)) { rs[threadIdx.x >> 6] = s; rs2[threadIdx.x >> 6] = s2; }
  __syncthreads();
  s  = rs[0] + rs[1] + rs[2] + rs[3];
  s2 = rs2[0] + rs2[1] + rs2[2] + rs2[3];
  const float mu = s * (1.f / DD);
  const float var = s2 * (1.f / DD) - mu * mu;
  const float rstd = rsqrtf(var + 1e-5f);
#pragma unroll
  for (int i = 0; i < 3; ++i) {
    int d = threadIdx.x + i * 256;
    out[(long)row * DD + d] = f2bf((vals[i] - mu) * rstd * g[d] + b[d]);
  }
}

// ---------------- V transpose: vt[z][d][t] ----------------
__global__ __launch_bounds__(256) void vtrans_k(const short* __restrict__ qkv,
                                                short* __restrict__ vt)
{
  const int tt = blockIdx.x;   // t-chunk of 64
  const int z  = blockIdx.y;   // b*H + h
  const int zb = z / HH, zh = z % HH;
  __shared__ short tile[64][65];
  for (int e = threadIdx.x; e < 64 * 64; e += 256) {
    int lt = e >> 6, d = e & 63;
    tile[lt][d] = qkv[(long)(zb * TT + tt * 64 + lt) * (3 * DD) + 2 * DD + zh * 64 + d];
  }
  __syncthreads();
  for (int e = threadIdx.x; e < 64 * 64; e += 256) {
    int d = e >> 6, lt = e & 63;
    vt[((long)z * 64 + d) * TT + tt * 64 + lt] = tile[lt][d];
  }
}

// ---------------- flash attention, 4-way kv-split ----------------
__global__ __launch_bounds__(256) void flash_k(const short* __restrict__ qkv,
                                               const short* __restrict__ vt,
                                               short* __restrict__ y)
{
  const int qt = (int)gridDim.x - 1 - (int)blockIdx.x;  // longest blocks first
  const int z  = blockIdx.y;
  const int zb = z / HH, zh = z % HH;
  const int w    = threadIdx.x >> 6;
  const int lane = threadIdx.x & 63;
  const int c = lane & 15, g = lane >> 4;

  __shared__ short Pl[4][16][40];
  __shared__ float Ol[4][16][64];
  __shared__ float ml[4][16], ll[4][16];

  const int qbase = qt * 16;
  const long rowQ = (long)(zb * TT + qbase + c) * (3 * DD) + zh * 64;

  bf16x8 qf[2];
  qf[0] = *(const bf16x8*)(qkv + rowQ + g * 8);
  qf[1] = *(const bf16x8*)(qkv + rowQ + 32 + g * 8);

  f32x4 O[4] = {};
  f32x4 mrun, lrun;
#pragma unroll
  for (int r = 0; r < 4; ++r) { mrun[r] = -1e30f; lrun[r] = 0.f; }

  const float CSC = 0.125f * 1.44269504089f;
  const int nt = (qbase + 15) / 32 + 1;

  for (int t = w; t < nt; t += 4) {
    const int k0 = t * 32;
    f32x4 acc[2] = {};
#pragma unroll
    for (int nf = 0; nf < 2; ++nf) {
      const long rowK = (long)(zb * TT + k0 + nf * 16 + c) * (3 * DD) + DD + zh * 64;
      bf16x8 kf0 = *(const bf16x8*)(qkv + rowK + g * 8);
      bf16x8 kf1 = *(const bf16x8*)(qkv + rowK + 32 + g * 8);
      acc[nf] = __builtin_amdgcn_mfma_f32_16x16x32_bf16(qf[0], kf0, acc[nf], 0, 0, 0);
      acc[nf] = __builtin_amdgcn_mfma_f32_16x16x32_bf16(qf[1], kf1, acc[nf], 0, 0, 0);
    }
    f32x4 tv[2];
    const int mask_needed = (k0 + 31 > qbase);
#pragma unroll
    for (int nf = 0; nf < 2; ++nf) {
      const int k_abs = k0 + nf * 16 + c;
#pragma unroll
      for (int r = 0; r < 4; ++r) {
        float val = acc[nf][r] * CSC;
        if (mask_needed && k_abs > qbase + g * 4 + r) val = -1e30f;
        tv[nf][r] = val;
      }
    }
    f32x4 rmax;
#pragma unroll
    for (int r = 0; r < 4; ++r) rmax[r] = fmaxf(tv[0][r], tv[1][r]);
#pragma unroll
    for (int off = 1; off < 16; off <<= 1) {
#pragma unroll
      for (int r = 0; r < 4; ++r) rmax[r] = fmaxf(rmax[r], __shfl_xor(rmax[r], off, 64));
    }
    f32x4 mnew, rfac;
#pragma unroll
    for (int r = 0; r < 4; ++r) {
      mnew[r] = fmaxf(mrun[r], rmax[r]);
      rfac[r] = exp2f(mrun[r] - mnew[r]);
      mrun[r] = mnew[r];
    }
    f32x4 e0, e1, rsum;
#pragma unroll
    for (int r = 0; r < 4; ++r) {
      e0[r] = exp2f(tv[0][r] - mnew[r]);
      e1[r] = exp2f(tv[1][r] - mnew[r]);
      rsum[r] = e0[r] + e1[r];
    }
#pragma unroll
    for (int off = 1; off < 16; off <<= 1) {
#pragma unroll
      for (int r = 0; r < 4; ++r) rsum[r] += __shfl_xor(rsum[r], off, 64);
    }
#pragma unroll
    for (int r = 0; r < 4; ++r) lrun[r] = lrun[r] * rfac[r] + rsum[r];
#pragma unroll
    for (int nf = 0; nf < 4; ++nf)
#pragma unroll
      for (int r = 0; r < 4; ++r) O[nf][r] *= rfac[r];
#pragma unroll
    for (int r = 0; r < 4; ++r) {
      Pl[w][g * 4 + r][c]      = f2bf(e0[r]);
      Pl[w][g * 4 + r][16 + c] = f2bf(e1[r]);
    }
    asm volatile("s_waitcnt lgkmcnt(0)" ::: "memory");
    const bf16x8 pf = *(const bf16x8*)&Pl[w][c][g * 8];
#pragma unroll
    for (int nf = 0; nf < 4; ++nf) {
      const bf16x8 vf = *(const bf16x8*)(vt + ((long)z * 64 + nf * 16 + c) * TT + k0 + g * 8);
      O[nf] = __builtin_amdgcn_mfma_f32_16x16x32_bf16(pf, vf, O[nf], 0, 0, 0);
    }
  }

  // ---- publish partials ----
#pragma unroll
  for (int nf = 0; nf < 4; ++nf)
#pragma unroll
    for (int r = 0; r < 4; ++r)
      Ol[w][g * 4 + r][nf * 16 + c] = O[nf][r];
  if (c == 0) {
#pragma unroll
    for (int r = 0; r < 4; ++r) { ml[w][g * 4 + r] = mrun[r]; ll[w][g * 4 + r] = lrun[r]; }
  }
  __syncthreads();

  // ---- merge 4 partials + normalize + write ----
  for (int e = threadIdx.x; e < 16 * 64; e += 256) {
    const int row = e >> 6, d = e & 63;
    const float M = fmaxf(fmaxf(ml[0][row], ml[1][row]), fmaxf(ml[2][row], ml[3][row]));
    float L = 0.f, Ov = 0.f;
#pragma unroll
    for (int u = 0; u < 4; ++u) {
      const float f = exp2f(ml[u][row] - M);
      L += ll[u][row] * f;
      Ov += Ol[u][row][d] * f;
    }
    y[(long)(zb * TT + qbase + row) * DD + zh * 64 + d] = f2bf(Ov / L);
  }
}

// ---------------- NT GEMM: C[m,n] = sum_k A[m,k] * B[n,k]  (+ epilogue) ----------------
// bf16 path: PIPE=true -> depth-2 prefetch, 3-buffer LDS, counted vmcnt
// (2*GPT steady state, never 0 mid-loop) for the ~1-2 block/CU layer regime;
// PIPE=false -> single-buffer sync (LM head: 25 blocks/CU self-pipelines).
// XOR chunk swizzle on global SOURCE (linear gload_lds dest) + same XOR on reads.
// EPI: 0 fp32*scale ; 1 bf16+bias ; 2 fp32 resid+acc+bias ; 3 bf16 gelu ; 4 bf16 plain
template<int BM, int BN, int BK, typename TB, int EPI, bool LMSWZ, bool PIPE>
__global__ __launch_bounds__(256) void gemm_nt(
    const short* __restrict__ A, const TB* __restrict__ Bm,
    const float* __restrict__ bias, const float* __restrict__ resid,
    void* __restrict__ Cout,
    int M, int N, int K, int lda, int ldb, int ldc,
    long aSB, long aSH, long bSB, long bSH, long cSB, long cSH,
    float scale, int causal)
{
  int n0, m0;
  if constexpr (LMSWZ) {
    const int l = blockIdx.x;
    const int x = l & 7;
    const int j = l >> 3;
    const int mt = j & 15;
    const int nl = j >> 4;
    const int npan = (N + BN - 1) / BN;
    const int q = npan >> 3, rr = npan & 7;
    const int cnt = q + (x < rr);
    if (nl >= cnt) return;
    const int nstart = x * q + (x < rr ? x : rr);
    n0 = (nstart + nl) * BN;
    m0 = mt * BM;
  } else {
    n0 = blockIdx.x * BN;
    m0 = blockIdx.y * BM;
  }
  if (causal && n0 >= m0 + BM) return;
  const int z = blockIdx.z;
  const int zb = z / HH, zh = z % HH;
  const short* Ag = A + zb * aSB + zh * aSH + (long)m0 * lda;
  const TB*    Bg = Bm + zb * bSB + zh * bSH;
  const long  cOff = zb * cSB + zh * cSH;

  constexpr int NBUF = PIPE ? 3 : 1;
  __shared__ __align__(16) short Als[NBUF][BM][BK];
  __shared__ __align__(16) short Bls[NBUF][BN][BK];

  const int tid = threadIdx.x;
  const int lane = tid & 63, wid = tid >> 6;
  constexpr int WTM = BM / 2, WTN = BN / 2;
  constexpr int FM = WTM / 16, FN = WTN / 16;
  const int wr = wid >> 1, wc = wid & 1;

  f32x4 acc[FM][FN] = {};
  const int kAoff = (lane >> 4) * 8;
  constexpr bool B_IS_F32 = (sizeof(TB) == 4);
  constexpr int CPR = BK / 8;            // 16B chunks per row
  constexpr int NCA = BM * CPR;
  constexpr int NCB = BN * CPR;
  constexpr int IA = NCA / 256, IB = NCB / 256;
  constexpr int GPT = IA + IB;           // gloads per thread per tile
  static_assert(CPR == 8, "swizzle assumes 128B rows (BK=64)");
  static_assert(B_IS_F32 || (NCA % 256 == 0 && NCB % 256 == 0), "chunk grid");

  // fragment compute over buffer `buf`
  auto compute = [&](int buf) {
#pragma unroll
    for (int kk = 0; kk < BK; kk += 32) {
      bf16x8 af[FM], bfr[FN];
#pragma unroll
      for (int mi = 0; mi < FM; ++mi) {
        const int Ra = wr * WTM + mi * 16 + (lane & 15);
        const int kca = (kk + kAoff) >> 3;
        af[mi] = *(const bf16x8*)&Als[buf][Ra][(kca ^ (Ra & 7)) << 3];
      }
#pragma unroll
      for (int ni = 0; ni < FN; ++ni) {
        const int Rb = wc * WTN + ni * 16 + (lane & 15);
        const int kcb = (kk + kAoff) >> 3;
        bfr[ni] = *(const bf16x8*)&Bls[buf][Rb][(kcb ^ (Rb & 7)) << 3];
      }
#pragma unroll
      for (int mi = 0; mi < FM; ++mi)
#pragma unroll
        for (int ni = 0; ni < FN; ++ni)
          acc[mi][ni] = __builtin_amdgcn_mfma_f32_16x16x32_bf16(af[mi], bfr[ni], acc[mi][ni], 0, 0, 0);
    }
  };

  if constexpr (!B_IS_F32) {
    // hoisted per-thread source pointers (advance by BK per staged tile)
    const short* ap[IA];
    const short* bp[IB];
#pragma unroll
    for (int i = 0; i < IA; ++i) {
      const int cch = i * 256 + tid;
      const int r = cch / CPR, kc = cch % CPR;
      ap[i] = Ag + (long)r * lda + ((kc ^ (r & 7)) << 3);
    }
#pragma unroll
    for (int i = 0; i < IB; ++i) {
      const int cch = i * 256 + tid;
      const int r = cch / CPR, kc = cch % CPR;
      int gr = n0 + r; gr = (gr < N) ? gr : (N - 1);
      bp[i] = (const short*)Bg + (long)gr * ldb + ((kc ^ (r & 7)) << 3);
    }
    const int ldsoff = wid * 64 * 16;    // wave-uniform base; HW adds lane*16

    auto stage = [&](int buf) {
#pragma unroll
      for (int i = 0; i < IA; ++i) {
        gload16(ap[i], (char*)&Als[buf][0][0] + i * 4096 + ldsoff);
        ap[i] += BK;
      }
#pragma unroll
      for (int i = 0; i < IB; ++i) {
        gload16(bp[i], (char*)&Bls[buf][0][0] + i * 4096 + ldsoff);
        bp[i] += BK;
      }
    };

    if constexpr (PIPE) {
      const int KT = K / BK;
      stage(0);
      if (KT > 1) stage(1);
      for (int kt = 0; kt < KT; ++kt) {
        const int cur = kt % 3;
        if (kt + 2 < KT) {
          stage((kt + 2) % 3);
          asm volatile("s_waitcnt vmcnt(%0)" :: "i"(2 * GPT));
        } else if (kt + 1 < KT) {
          asm volatile("s_waitcnt vmcnt(%0)" :: "i"(GPT));
        } else {
          asm volatile("s_waitcnt vmcnt(0)");
        }
        __builtin_amdgcn_sched_barrier(0);
        __builtin_amdgcn_s_barrier();
        __builtin_amdgcn_sched_barrier(0);
        compute(cur);
        asm volatile("" ::: "memory");
        __builtin_amdgcn_s_barrier();
        __builtin_amdgcn_sched_barrier(0);
      }
    } else {
      const int KT = K / BK;
      for (int kt = 0; kt < KT; ++kt) {
        stage(0);
        __syncthreads();
        compute(0);
        __syncthreads();
      }
    }
  } else {
    // --- fp32 fallback: synchronous single-buffer staging with on-the-fly cvt ---
    for (int k0 = 0; k0 < K; k0 += BK) {
#pragma unroll
      for (int cc = tid; cc < BM * (BK / 8); cc += 256) {
        int r = cc / (BK / 8), kc = cc % (BK / 8);
        const uint4 v = *(const uint4*)(Ag + (long)r * lda + k0 + kc * 8);
        *(uint4*)((char*)&Als[0][r][0] + ((kc ^ (r & 7)) << 4)) = v;
      }
#pragma unroll
      for (int cc = tid; cc < BN * (BK / 4); cc += 256) {
        int r = cc / (BK / 4), kc = cc % (BK / 4);
        int gr = n0 + r; gr = (gr < N) ? gr : (N - 1);
        const float4 v = *(const float4*)((const float*)Bg + (long)gr * ldb + k0 + kc * 4);
        short4 h4;
        h4.x = f2bf(v.x); h4.y = f2bf(v.y); h4.z = f2bf(v.z); h4.w = f2bf(v.w);
        *(short4*)((char*)&Bls[0][r][0] + ((kc * 8) ^ ((r & 7) << 4))) = h4;
      }
      __syncthreads();
      compute(0);
      __syncthreads();
    }
  }

  const int rq = (lane >> 4) << 2;
  const int cl = lane & 15;
#pragma unroll
  for (int mi = 0; mi < FM; ++mi) {
#pragma unroll
    for (int ni = 0; ni < FN; ++ni) {
      const int cg = n0 + wc * WTN + ni * 16 + cl;
      if (cg >= N) continue;
      const int rbase = m0 + wr * WTM + mi * 16 + rq;
#pragma unroll
      for (int q = 0; q < 4; ++q) {
        const long cidx = cOff + (long)(rbase + q) * ldc + cg;
        const float v = acc[mi][ni][q];
        if constexpr (EPI == 0) {
          ((float*)Cout)[cidx] = v * scale;
        } else if constexpr (EPI == 1) {
          ((short*)Cout)[cidx] = f2bf(v + bias[cg]);
        } else if constexpr (EPI == 2) {
          ((float*)Cout)[cidx] = resid[cidx] + v + bias[cg];
        } else if constexpr (EPI == 3) {
          const float zz = v + bias[cg];
          ((short*)Cout)[cidx] = f2bf(0.5f * zz * (1.f + erff(zz * 0.70710678118f)));
        } else {
          ((short*)Cout)[cidx] = f2bf(v);
        }
      }
    }
  }
}

// ---------------- model driver ----------------
template<typename TB>
static void run_model(const int* idx, const float* tok_f, const float* pos,
                      const TB* wqkv, const float* bqkv, const TB* wproj, const float* bproj,
                      const float* ln1g, const float* ln1b, const float* ln2g, const float* ln2b,
                      const TB* w1, const float* b1, const TB* w2, const float* b2,
                      const float* lnfg, const float* lnfb, const TB* tok_w,
                      float* xa, float* xb, short* hbf, short* qkv, short* vt,
                      short* ybf, short* ffb,
                      float* out, hipStream_t stream)
{
  embed_k<<<dim3(MROWS * DD / 256), 256, 0, stream>>>(idx, tok_f, pos, xa);

  float* xc = xa;
  float* xn = xb;
  for (int l = 0; l < LL; ++l) {
    ln_k<<<dim3(MROWS), 256, 0, stream>>>(xc, ln1g + l * DD, ln1b + l * DD, hbf);
    // qkv: BN=64 -> 576 blocks (TLP regime), depth-2 pipe
    gemm_nt<128, 64, 64, TB, 1, false, true><<<dim3(36, 16, 1), 256, 0, stream>>>(
        hbf, wqkv + (long)l * 3 * DD * DD, bqkv + l * 3 * DD, nullptr, qkv,
        MROWS, 3 * DD, DD, DD, DD, 3 * DD, 0, 0, 0, 0, 0, 0, 1.f, 0);
    vtrans_k<<<dim3(16, 24), 256, 0, stream>>>(qkv, vt);
    flash_k<<<dim3(64, 24), 256, 0, stream>>>(qkv, vt, ybf);
    gemm_nt<64, 64, 64, TB, 2, false, true><<<dim3(12, 32, 1), 256, 0, stream>>>(
        ybf, wproj + (long)l * DD * DD, bproj + l * DD, xc, xn,
        MROWS, DD, DD, DD, DD, DD, 0, 0, 0, 0, 0, 0, 1.f, 0);
    ln_k<<<dim3(MROWS), 256, 0, stream>>>(xn, ln2g + l * DD, ln2b + l * DD, hbf);
    // fc1: BN=64 -> 768 blocks
    gemm_nt<128, 64, 64, TB, 3, false, true><<<dim3(48, 16, 1), 256, 0, stream>>>(
        hbf, w1 + (long)l * 4 * DD * DD, b1 + l * 4 * DD, nullptr, ffb,
        MROWS, 4 * DD, DD, DD, DD, 4 * DD, 0, 0, 0, 0, 0, 0, 1.f, 0);
    gemm_nt<64, 64, 64, TB, 2, false, true><<<dim3(12, 32, 1), 256, 0, stream>>>(
        ffb, w2 + (long)l * DD * 4 * DD, b2 + l * DD, xn, xc,
        MROWS, DD, 4 * DD, 4 * DD, 4 * DD, DD, 0, 0, 0, 0, 0, 0, 1.f, 0);
  }
  ln_k<<<dim3(MROWS), 256, 0, stream>>>(xc, lnfg, lnfb, hbf);
  // LM head: single-buffer (25 blocks/CU self-pipelines), XCD-pinned 1-D grid
  gemm_nt<128, 128, 64, TB, 0, true, false><<<dim3(6400, 1, 1), 256, 0, stream>>>(
      hbf, tok_w, nullptr, nullptr, out,
      MROWS, VV, DD, DD, DD, VV, 0, 0, 0, 0, 0, 0, 1.f, 0);
}

extern "C" void kernel_launch(void* const* d_in, const int* in_sizes, int n_in,
                              void* d_out, int out_size, void* d_ws, size_t ws_size,
                              hipStream_t stream)
{
  const int*   idx  = (const int*)d_in[0];
  const float* tok  = (const float*)d_in[1];
  const float* pos  = (const float*)d_in[2];
  const float* wqkv = (const float*)d_in[3];
  const float* bqkv = (const float*)d_in[4];
  const float* wproj= (const float*)d_in[5];
  const float* bproj= (const float*)d_in[6];
  const float* ln1g = (const float*)d_in[7];
  const float* ln1b = (const float*)d_in[8];
  const float* ln2g = (const float*)d_in[9];
  const float* ln2b = (const float*)d_in[10];
  const float* w1   = (const float*)d_in[11];
  const float* b1   = (const float*)d_in[12];
  const float* w2   = (const float*)d_in[13];
  const float* b2   = (const float*)d_in[14];
  const float* lnfg = (const float*)d_in[15];
  const float* lnfb = (const float*)d_in[16];
  float* out = (float*)d_out;

  const long E_WQKV = (long)LL * 3 * DD * DD;
  const long E_WPRJ = (long)LL * DD * DD;
  const long E_W1   = (long)LL * 4 * DD * DD;
  const long E_W2   = E_W1;
  const long E_TOK  = (long)VV * DD;
  const long E_WSUM = E_WQKV + E_WPRJ + E_W1 + E_W2 + E_TOK;

  const size_t NEED_B = 44040192;
  const size_t NEED_A = NEED_B + 2 * (size_t)E_WSUM;

  if (ws_size < NEED_B) return;
  const bool bf16w = (ws_size >= NEED_A);

  char* ws = (char*)d_ws;
  short *wqkv_h = nullptr, *wprj_h = nullptr, *w1_h = nullptr, *w2_h = nullptr, *tok_h = nullptr;
  if (bf16w) {
    wqkv_h = (short*)ws; ws += E_WQKV * 2;
    wprj_h = (short*)ws; ws += E_WPRJ * 2;
    w1_h   = (short*)ws; ws += E_W1 * 2;
    w2_h   = (short*)ws; ws += E_W2 * 2;
    tok_h  = (short*)ws; ws += E_TOK * 2;
  }
  float* xa  = (float*)ws; ws += (size_t)MROWS * DD * 4;
  float* xb  = (float*)ws; ws += (size_t)MROWS * DD * 4;
  short* hbf = (short*)ws; ws += (size_t)MROWS * DD * 2;
  short* qkv = (short*)ws; ws += (size_t)MROWS * 3 * DD * 2;
  short* vt  = (short*)ws; ws += (size_t)24 * 64 * TT * 2;
  short* ybf = (short*)ws; ws += (size_t)MROWS * DD * 2;
  short* ffb = (short*)ws; ws += (size_t)MROWS * 4 * DD * 2;

  if (bf16w) {
    cvt_k<<<dim3(4096), 256, 0, stream>>>(wqkv, wqkv_h, E_WQKV / 4);
    cvt_k<<<dim3(4096), 256, 0, stream>>>(wproj, wprj_h, E_WPRJ / 4);
    cvt_k<<<dim3(4096), 256, 0, stream>>>(w1, w1_h, E_W1 / 4);
    cvt_k<<<dim3(4096), 256, 0, stream>>>(w2, w2_h, E_W2 / 4);
    cvt_k<<<dim3(4096), 256, 0, stream>>>(tok, tok_h, E_TOK / 4);
    run_model<short>(idx, tok, pos, wqkv_h, bqkv, wprj_h, bproj,
                     ln1g, ln1b, ln2g, ln2b, w1_h, b1, w2_h, b2, lnfg, lnfb, tok_h,
                     xa, xb, hbf, qkv, vt, ybf, ffb, out, stream);
  } else {
    run_model<float>(idx, tok, pos, wqkv, bqkv, wproj, bproj,
                     ln1g, ln1b, ln2g, ln2b, w1, b1, w2, b2, lnfg, lnfb, tok,
                     xa, xb, hbf, qkv, vt, ybf, ffb, out, stream);
  }
}

// Round 10
// 2231.156 us; speedup vs baseline: 1.2077x; 1.1274x over previous
//
#include <hip/hip_runtime.h>
#include <hip/hip_bf16.h>

#define TT 1024
#define DD 768
#define HH 12
#define LL 12
#define VV 50257
#define MROWS 2048   // B*T

typedef __attribute__((ext_vector_type(4))) float f32x4;
typedef __attribute__((ext_vector_type(8))) short bf16x8;

__device__ __forceinline__ short f2bf(float f) {
  __hip_bfloat16 h = __float2bfloat16(f);
  short s;
  __builtin_memcpy(&s, &h, 2);
  return s;
}

__device__ __forceinline__ void gload16(const void* g, void* l) {
  __builtin_amdgcn_global_load_lds(
      (const __attribute__((address_space(1))) unsigned int*)g,
      (__attribute__((address_space(3))) unsigned int*)l, 16, 0, 0);
}

__device__ __forceinline__ float wsum(float v) {
#pragma unroll
  for (int o = 32; o; o >>= 1) v += __shfl_xor(v, o, 64);
  return v;
}

// ---------------- fp32 -> bf16 weight conversion ----------------
__global__ __launch_bounds__(256) void cvt_k(const float* __restrict__ src,
                                             short* __restrict__ dst, long n4)
{
  const long stride = (long)gridDim.x * 256;
  for (long i = (long)blockIdx.x * 256 + threadIdx.x; i < n4; i += stride) {
    const float4 v = ((const float4*)src)[i];
    short4 h;
    h.x = f2bf(v.x); h.y = f2bf(v.y); h.z = f2bf(v.z); h.w = f2bf(v.w);
    ((short4*)dst)[i] = h;
  }
}

// ---------------- embedding ----------------
__global__ __launch_bounds__(256) void embed_k(const int* __restrict__ idx,
    const float* __restrict__ tok, const float* __restrict__ pos,
    float* __restrict__ x)
{
  int i = blockIdx.x * 256 + threadIdx.x;
  int d = i % DD;
  int bt = i / DD;
  int t = bt & (TT - 1);
  x[i] = tok[(long)idx[bt] * DD + d] + pos[t * DD + d];
}

// ---------------- LayerNorm: 1 wave per row, 4 rows per block ----------------
__global__ __launch_bounds__(256) void ln_k(const float* __restrict__ x,
    const float* __restrict__ g, const float* __restrict__ b,
    short* __restrict__ out)
{
  const int w = threadIdx.x >> 6;
  const int lane = threadIdx.x & 63;
  const int row = blockIdx.x * 4 + w;
  const float* xr = x + (long)row * DD;
  float4 v[3];
  float s = 0.f, s2 = 0.f;
#pragma unroll
  for (int i = 0; i < 3; ++i) {
    v[i] = ((const float4*)xr)[lane + i * 64];
    s  += v[i].x + v[i].y + v[i].z + v[i].w;
    s2 += v[i].x * v[i].x + v[i].y * v[i].y + v[i].z * v[i].z + v[i].w * v[i].w;
  }
  s = wsum(s); s2 = wsum(s2);
  const float mu = s * (1.f / DD);
  const float var = s2 * (1.f / DD) - mu * mu;
  const float rstd = rsqrtf(var + 1e-5f);
#pragma unroll
  for (int i = 0; i < 3; ++i) {
    const int d0 = (lane + i * 64) * 4;
    short4 h;
    h.x = f2bf((v[i].x - mu) * rstd * g[d0 + 0] + b[d0 + 0]);
    h.y = f2bf((v[i].y - mu) * rstd * g[d0 + 1] + b[d0 + 1]);
    h.z = f2bf((v[i].z - mu) * rstd * g[d0 + 2] + b[d0 + 2]);
    h.w = f2bf((v[i].w - mu) * rstd * g[d0 + 3] + b[d0 + 3]);
    ((short4*)(out + (long)row * DD))[lane + i * 64] = h;
  }
}

// ---------------- flash attention, 4-way kv-split ----------------
__global__ __launch_bounds__(256) void flash_k(const short* __restrict__ qkv,
                                               const short* __restrict__ vt,
                                               short* __restrict__ y)
{
  const int qt = (int)gridDim.x - 1 - (int)blockIdx.x;  // longest blocks first
  const int z  = blockIdx.y;
  const int zb = z / HH, zh = z % HH;
  const int w    = threadIdx.x >> 6;
  const int lane = threadIdx.x & 63;
  const int c = lane & 15, g = lane >> 4;

  __shared__ short Pl[4][16][40];
  __shared__ float Ol[4][16][64];
  __shared__ float ml[4][16], ll[4][16];

  const int qbase = qt * 16;
  const long rowQ = (long)(zb * TT + qbase + c) * (3 * DD) + zh * 64;

  bf16x8 qf[2];
  qf[0] = *(const bf16x8*)(qkv + rowQ + g * 8);
  qf[1] = *(const bf16x8*)(qkv + rowQ + 32 + g * 8);

  f32x4 O[4] = {};
  f32x4 mrun, lrun;
#pragma unroll
  for (int r = 0; r < 4; ++r) { mrun[r] = -1e30f; lrun[r] = 0.f; }

  const float CSC = 0.125f * 1.44269504089f;
  const int nt = (qbase + 15) / 32 + 1;

  for (int t = w; t < nt; t += 4) {
    const int k0 = t * 32;
    f32x4 acc[2] = {};
#pragma unroll
    for (int nf = 0; nf < 2; ++nf) {
      const long rowK = (long)(zb * TT + k0 + nf * 16 + c) * (3 * DD) + DD + zh * 64;
      bf16x8 kf0 = *(const bf16x8*)(qkv + rowK + g * 8);
      bf16x8 kf1 = *(const bf16x8*)(qkv + rowK + 32 + g * 8);
      acc[nf] = __builtin_amdgcn_mfma_f32_16x16x32_bf16(qf[0], kf0, acc[nf], 0, 0, 0);
      acc[nf] = __builtin_amdgcn_mfma_f32_16x16x32_bf16(qf[1], kf1, acc[nf], 0, 0, 0);
    }
    f32x4 tv[2];
    const int mask_needed = (k0 + 31 > qbase);
#pragma unroll
    for (int nf = 0; nf < 2; ++nf) {
      const int k_abs = k0 + nf * 16 + c;
#pragma unroll
      for (int r = 0; r < 4; ++r) {
        float val = acc[nf][r] * CSC;
        if (mask_needed && k_abs > qbase + g * 4 + r) val = -1e30f;
        tv[nf][r] = val;
      }
    }
    f32x4 rmax;
#pragma unroll
    for (int r = 0; r < 4; ++r) rmax[r] = fmaxf(tv[0][r], tv[1][r]);
#pragma unroll
    for (int off = 1; off < 16; off <<= 1) {
#pragma unroll
      for (int r = 0; r < 4; ++r) rmax[r] = fmaxf(rmax[r], __shfl_xor(rmax[r], off, 64));
    }
    f32x4 mnew, rfac;
#pragma unroll
    for (int r = 0; r < 4; ++r) {
      mnew[r] = fmaxf(mrun[r], rmax[r]);
      rfac[r] = exp2f(mrun[r] - mnew[r]);
      mrun[r] = mnew[r];
    }
    f32x4 e0, e1, rsum;
#pragma unroll
    for (int r = 0; r < 4; ++r) {
      e0[r] = exp2f(tv[0][r] - mnew[r]);
      e1[r] = exp2f(tv[1][r] - mnew[r]);
      rsum[r] = e0[r] + e1[r];
    }
#pragma unroll
    for (int off = 1; off < 16; off <<= 1) {
#pragma unroll
      for (int r = 0; r < 4; ++r) rsum[r] += __shfl_xor(rsum[r], off, 64);
    }
#pragma unroll
    for (int r = 0; r < 4; ++r) lrun[r] = lrun[r] * rfac[r] + rsum[r];
#pragma unroll
    for (int nf = 0; nf < 4; ++nf)
#pragma unroll
      for (int r = 0; r < 4; ++r) O[nf][r] *= rfac[r];
#pragma unroll
    for (int r = 0; r < 4; ++r) {
      Pl[w][g * 4 + r][c]      = f2bf(e0[r]);
      Pl[w][g * 4 + r][16 + c] = f2bf(e1[r]);
    }
    asm volatile("s_waitcnt lgkmcnt(0)" ::: "memory");
    const bf16x8 pf = *(const bf16x8*)&Pl[w][c][g * 8];
#pragma unroll
    for (int nf = 0; nf < 4; ++nf) {
      const bf16x8 vf = *(const bf16x8*)(vt + ((long)z * 64 + nf * 16 + c) * TT + k0 + g * 8);
      O[nf] = __builtin_amdgcn_mfma_f32_16x16x32_bf16(pf, vf, O[nf], 0, 0, 0);
    }
  }

  // ---- publish partials ----
#pragma unroll
  for (int nf = 0; nf < 4; ++nf)
#pragma unroll
    for (int r = 0; r < 4; ++r)
      Ol[w][g * 4 + r][nf * 16 + c] = O[nf][r];
  if (c == 0) {
#pragma unroll
    for (int r = 0; r < 4; ++r) { ml[w][g * 4 + r] = mrun[r]; ll[w][g * 4 + r] = lrun[r]; }
  }
  __syncthreads();

  // ---- merge 4 partials + normalize + write ----
  for (int e = threadIdx.x; e < 16 * 64; e += 256) {
    const int row = e >> 6, d = e & 63;
    const float M = fmaxf(fmaxf(ml[0][row], ml[1][row]), fmaxf(ml[2][row], ml[3][row]));
    float L = 0.f, Ov = 0.f;
#pragma unroll
    for (int u = 0; u < 4; ++u) {
      const float f = exp2f(ml[u][row] - M);
      L += ll[u][row] * f;
      Ov += Ol[u][row][d] * f;
    }
    y[(long)(zb * TT + qbase + row) * DD + zh * 64 + d] = f2bf(Ov / L);
  }
}

// ---------------- NT GEMM: C[m,n] = sum_k A[m,k] * B[n,k]  (+ epilogue) ----------------
// bf16: PIPE=true -> 2-phase dbuf, counted vmcnt(GPT) (r7-verified layer config);
// PIPE=false -> single-buffer (LM head, 25 blocks/CU self-pipelines).
// XOR chunk swizzle on global SOURCE (linear gload_lds dest) + same XOR on reads.
// EPI: 0 fp32*scale ; 1 bf16+bias ; 2 fp32 resid+acc+bias ; 3 bf16 gelu ;
//      5 qkv fused: Q/K -> bf16+bias to Cout; V -> bf16+bias TRANSPOSED to vt
//        (vt passed via `resid` arg; kills the standalone vtrans kernel).
template<int BM, int BN, int BK, typename TB, int EPI, bool LMSWZ, bool PIPE>
__global__ __launch_bounds__(256) void gemm_nt(
    const short* __restrict__ A, const TB* __restrict__ Bm,
    const float* __restrict__ bias, const float* __restrict__ resid,
    void* __restrict__ Cout,
    int M, int N, int K, int lda, int ldb, int ldc,
    long aSB, long aSH, long bSB, long bSH, long cSB, long cSH,
    float scale, int causal)
{
  int n0, m0;
  if constexpr (LMSWZ) {
    const int l = blockIdx.x;
    const int x = l & 7;
    const int j = l >> 3;
    const int mt = j & 15;
    const int nl = j >> 4;
    const int npan = (N + BN - 1) / BN;
    const int q = npan >> 3, rr = npan & 7;
    const int cnt = q + (x < rr);
    if (nl >= cnt) return;
    const int nstart = x * q + (x < rr ? x : rr);
    n0 = (nstart + nl) * BN;
    m0 = mt * BM;
  } else {
    n0 = blockIdx.x * BN;
    m0 = blockIdx.y * BM;
  }
  if (causal && n0 >= m0 + BM) return;
  const int z = blockIdx.z;
  const int zb = z / HH, zh = z % HH;
  const short* Ag = A + zb * aSB + zh * aSH + (long)m0 * lda;
  const TB*    Bg = Bm + zb * bSB + zh * bSH;
  const long  cOff = zb * cSB + zh * cSH;

  constexpr int NBUF = PIPE ? 2 : 1;
  __shared__ __align__(16) short Als[NBUF][BM][BK];
  __shared__ __align__(16) short Bls[NBUF][BN][BK];

  const int tid = threadIdx.x;
  const int lane = tid & 63, wid = tid >> 6;
  constexpr int WTM = BM / 2, WTN = BN / 2;
  constexpr int FM = WTM / 16, FN = WTN / 16;
  const int wr = wid >> 1, wc = wid & 1;

  f32x4 acc[FM][FN] = {};
  const int kAoff = (lane >> 4) * 8;
  constexpr bool B_IS_F32 = (sizeof(TB) == 4);
  constexpr int CPR = BK / 8;            // 16B chunks per row
  constexpr int NCA = BM * CPR;
  constexpr int NCB = BN * CPR;
  constexpr int IA = NCA / 256, IB = NCB / 256;
  constexpr int GPT = IA + IB;           // gloads per thread per tile
  static_assert(CPR == 8, "swizzle assumes 128B rows (BK=64)");
  static_assert(B_IS_F32 || (NCA % 256 == 0 && NCB % 256 == 0), "chunk grid");

  auto compute = [&](int buf) {
#pragma unroll
    for (int kk = 0; kk < BK; kk += 32) {
      bf16x8 af[FM], bfr[FN];
#pragma unroll
      for (int mi = 0; mi < FM; ++mi) {
        const int Ra = wr * WTM + mi * 16 + (lane & 15);
        const int kca = (kk + kAoff) >> 3;
        af[mi] = *(const bf16x8*)&Als[buf][Ra][(kca ^ (Ra & 7)) << 3];
      }
#pragma unroll
      for (int ni = 0; ni < FN; ++ni) {
        const int Rb = wc * WTN + ni * 16 + (lane & 15);
        const int kcb = (kk + kAoff) >> 3;
        bfr[ni] = *(const bf16x8*)&Bls[buf][Rb][(kcb ^ (Rb & 7)) << 3];
      }
#pragma unroll
      for (int mi = 0; mi < FM; ++mi)
#pragma unroll
        for (int ni = 0; ni < FN; ++ni)
          acc[mi][ni] = __builtin_amdgcn_mfma_f32_16x16x32_bf16(af[mi], bfr[ni], acc[mi][ni], 0, 0, 0);
    }
  };

  if constexpr (!B_IS_F32) {
    const short* ap[IA];
    const short* bp[IB];
#pragma unroll
    for (int i = 0; i < IA; ++i) {
      const int cch = i * 256 + tid;
      const int r = cch / CPR, kc = cch % CPR;
      ap[i] = Ag + (long)r * lda + ((kc ^ (r & 7)) << 3);
    }
#pragma unroll
    for (int i = 0; i < IB; ++i) {
      const int cch = i * 256 + tid;
      const int r = cch / CPR, kc = cch % CPR;
      int gr = n0 + r; gr = (gr < N) ? gr : (N - 1);
      bp[i] = (const short*)Bg + (long)gr * ldb + ((kc ^ (r & 7)) << 3);
    }
    const int ldsoff = wid * 64 * 16;    // wave-uniform base; HW adds lane*16

    auto stage = [&](int buf) {
#pragma unroll
      for (int i = 0; i < IA; ++i) {
        gload16(ap[i], (char*)&Als[buf][0][0] + i * 4096 + ldsoff);
        ap[i] += BK;
      }
#pragma unroll
      for (int i = 0; i < IB; ++i) {
        gload16(bp[i], (char*)&Bls[buf][0][0] + i * 4096 + ldsoff);
        bp[i] += BK;
      }
    };

    if constexpr (PIPE) {
      const int KT = K / BK;
      stage(0);
      for (int kt = 0; kt < KT; ++kt) {
        const int cur = kt & 1;
        if (kt + 1 < KT) {
          stage(cur ^ 1);
          asm volatile("s_waitcnt vmcnt(%0)" :: "i"(GPT));
        } else {
          asm volatile("s_waitcnt vmcnt(0)");
        }
        __builtin_amdgcn_sched_barrier(0);
        __builtin_amdgcn_s_barrier();
        __builtin_amdgcn_sched_barrier(0);
        compute(cur);
        asm volatile("" ::: "memory");
        __builtin_amdgcn_s_barrier();
        __builtin_amdgcn_sched_barrier(0);
      }
    } else {
      const int KT = K / BK;
      for (int kt = 0; kt < KT; ++kt) {
        stage(0);
        __syncthreads();
        compute(0);
        __syncthreads();
      }
    }
  } else {
    // --- fp32 fallback: synchronous single-buffer staging with on-the-fly cvt ---
    for (int k0 = 0; k0 < K; k0 += BK) {
#pragma unroll
      for (int cc = tid; cc < BM * (BK / 8); cc += 256) {
        int r = cc / (BK / 8), kc = cc % (BK / 8);
        const uint4 v = *(const uint4*)(Ag + (long)r * lda + k0 + kc * 8);
        *(uint4*)((char*)&Als[0][r][0] + ((kc ^ (r & 7)) << 4)) = v;
      }
#pragma unroll
      for (int cc = tid; cc < BN * (BK / 4); cc += 256) {
        int r = cc / (BK / 4), kc = cc % (BK / 4);
        int gr = n0 + r; gr = (gr < N) ? gr : (N - 1);
        const float4 v = *(const float4*)((const float*)Bg + (long)gr * ldb + k0 + kc * 4);
        short4 h4;
        h4.x = f2bf(v.x); h4.y = f2bf(v.y); h4.z = f2bf(v.z); h4.w = f2bf(v.w);
        *(short4*)((char*)&Bls[0][r][0] + ((kc * 8) ^ ((r & 7) << 4))) = h4;
      }
      __syncthreads();
      compute(0);
      __syncthreads();
    }
  }

  const int rq = (lane >> 4) << 2;
  const int cl = lane & 15;
#pragma unroll
  for (int mi = 0; mi < FM; ++mi) {
#pragma unroll
    for (int ni = 0; ni < FN; ++ni) {
      const int cg = n0 + wc * WTN + ni * 16 + cl;
      if (cg >= N) continue;
      const int rbase = m0 + wr * WTM + mi * 16 + rq;
      if constexpr (EPI == 5) {
        if (cg >= 2 * DD) {
          // V column -> transposed vt[(b*HH+h)*64 + d][t], 4 t-consecutive = short4
          const int hh = (cg - 2 * DD) >> 6, dd2 = (cg - 2 * DD) & 63;
          const int bI = rbase >> 10, tI = rbase & (TT - 1);
          const float bv = bias[cg];
          short4 h4;
          h4.x = f2bf(acc[mi][ni][0] + bv);
          h4.y = f2bf(acc[mi][ni][1] + bv);
          h4.z = f2bf(acc[mi][ni][2] + bv);
          h4.w = f2bf(acc[mi][ni][3] + bv);
          short* vtp = (short*)(void*)resid;
          *(short4*)(vtp + (((long)(bI * HH + hh) * 64 + dd2) << 10) + tI) = h4;
        } else {
#pragma unroll
          for (int q = 0; q < 4; ++q)
            ((short*)Cout)[(long)(rbase + q) * ldc + cg] = f2bf(acc[mi][ni][q] + bias[cg]);
        }
        continue;
      }
#pragma unroll
      for (int q = 0; q < 4; ++q) {
        const long cidx = cOff + (long)(rbase + q) * ldc + cg;
        const float v = acc[mi][ni][q];
        if constexpr (EPI == 0) {
          ((float*)Cout)[cidx] = v * scale;
        } else if constexpr (EPI == 1) {
          ((short*)Cout)[cidx] = f2bf(v + bias[cg]);
        } else if constexpr (EPI == 2) {
          ((float*)Cout)[cidx] = resid[cidx] + v + bias[cg];
        } else if constexpr (EPI == 3) {
          const float zz = v + bias[cg];
          ((short*)Cout)[cidx] = f2bf(0.5f * zz * (1.f + erff(zz * 0.70710678118f)));
        } else {
          ((short*)Cout)[cidx] = f2bf(v);
        }
      }
    }
  }
}

// ---------------- model driver ----------------
template<typename TB>
static void run_model(const int* idx, const float* tok_f, const float* pos,
                      const TB* wqkv, const float* bqkv, const TB* wproj, const float* bproj,
                      const float* ln1g, const float* ln1b, const float* ln2g, const float* ln2b,
                      const TB* w1, const float* b1, const TB* w2, const float* b2,
                      const float* lnfg, const float* lnfb, const TB* tok_w,
                      float* xa, float* xb, short* hbf, short* qkv, short* vt,
                      short* ybf, short* ffb,
                      float* out, hipStream_t stream)
{
  embed_k<<<dim3(MROWS * DD / 256), 256, 0, stream>>>(idx, tok_f, pos, xa);

  float* xc = xa;
  float* xn = xb;
  for (int l = 0; l < LL; ++l) {
    ln_k<<<dim3(MROWS / 4), 256, 0, stream>>>(xc, ln1g + l * DD, ln1b + l * DD, hbf);
    // qkv (fused V-transpose epilogue): BN=64 -> 576 blocks, 2-buf pipe
    gemm_nt<128, 64, 64, TB, 5, false, true><<<dim3(36, 16, 1), 256, 0, stream>>>(
        hbf, wqkv + (long)l * 3 * DD * DD, bqkv + l * 3 * DD, (const float*)vt, qkv,
        MROWS, 3 * DD, DD, DD, DD, 3 * DD, 0, 0, 0, 0, 0, 0, 1.f, 0);
    flash_k<<<dim3(64, 24), 256, 0, stream>>>(qkv, vt, ybf);
    gemm_nt<64, 64, 64, TB, 2, false, true><<<dim3(12, 32, 1), 256, 0, stream>>>(
        ybf, wproj + (long)l * DD * DD, bproj + l * DD, xc, xn,
        MROWS, DD, DD, DD, DD, DD, 0, 0, 0, 0, 0, 0, 1.f, 0);
    ln_k<<<dim3(MROWS / 4), 256, 0, stream>>>(xn, ln2g + l * DD, ln2b + l * DD, hbf);
    gemm_nt<128, 64, 64, TB, 3, false, true><<<dim3(48, 16, 1), 256, 0, stream>>>(
        hbf, w1 + (long)l * 4 * DD * DD, b1 + l * 4 * DD, nullptr, ffb,
        MROWS, 4 * DD, DD, DD, DD, 4 * DD, 0, 0, 0, 0, 0, 0, 1.f, 0);
    gemm_nt<64, 64, 64, TB, 2, false, true><<<dim3(12, 32, 1), 256, 0, stream>>>(
        ffb, w2 + (long)l * DD * 4 * DD, b2 + l * DD, xn, xc,
        MROWS, DD, 4 * DD, 4 * DD, 4 * DD, DD, 0, 0, 0, 0, 0, 0, 1.f, 0);
  }
  ln_k<<<dim3(MROWS / 4), 256, 0, stream>>>(xc, lnfg, lnfb, hbf);
  gemm_nt<128, 128, 64, TB, 0, true, false><<<dim3(6400, 1, 1), 256, 0, stream>>>(
      hbf, tok_w, nullptr, nullptr, out,
      MROWS, VV, DD, DD, DD, VV, 0, 0, 0, 0, 0, 0, 1.f, 0);
}

extern "C" void kernel_launch(void* const* d_in, const int* in_sizes, int n_in,
                              void* d_out, int out_size, void* d_ws, size_t ws_size,
                              hipStream_t stream)
{
  const int*   idx  = (const int*)d_in[0];
  const float* tok  = (const float*)d_in[1];
  const float* pos  = (const float*)d_in[2];
  const float* wqkv = (const float*)d_in[3];
  const float* bqkv = (const float*)d_in[4];
  const float* wproj= (const float*)d_in[5];
  const float* bproj= (const float*)d_in[6];
  const float* ln1g = (const float*)d_in[7];
  const float* ln1b = (const float*)d_in[8];
  const float* ln2g = (const float*)d_in[9];
  const float* ln2b = (const float*)d_in[10];
  const float* w1   = (const float*)d_in[11];
  const float* b1   = (const float*)d_in[12];
  const float* w2   = (const float*)d_in[13];
  const float* b2   = (const float*)d_in[14];
  const float* lnfg = (const float*)d_in[15];
  const float* lnfb = (const float*)d_in[16];
  float* out = (float*)d_out;

  const long E_WQKV = (long)LL * 3 * DD * DD;
  const long E_WPRJ = (long)LL * DD * DD;
  const long E_W1   = (long)LL * 4 * DD * DD;
  const long E_W2   = E_W1;
  const long E_TOK  = (long)VV * DD;
  const long E_WSUM = E_WQKV + E_WPRJ + E_W1 + E_W2 + E_TOK;

  const size_t NEED_B = 44040192;
  const size_t NEED_A = NEED_B + 2 * (size_t)E_WSUM;

  if (ws_size < NEED_B) return;
  const bool bf16w = (ws_size >= NEED_A);

  char* ws = (char*)d_ws;
  short *wqkv_h = nullptr, *wprj_h = nullptr, *w1_h = nullptr, *w2_h = nullptr, *tok_h = nullptr;
  if (bf16w) {
    wqkv_h = (short*)ws; ws += E_WQKV * 2;
    wprj_h = (short*)ws; ws += E_WPRJ * 2;
    w1_h   = (short*)ws; ws += E_W1 * 2;
    w2_h   = (short*)ws; ws += E_W2 * 2;
    tok_h  = (short*)ws; ws += E_TOK * 2;
  }
  float* xa  = (float*)ws; ws += (size_t)MROWS * DD * 4;
  float* xb  = (float*)ws; ws += (size_t)MROWS * DD * 4;
  short* hbf = (short*)ws; ws += (size_t)MROWS * DD * 2;
  short* qkv = (short*)ws; ws += (size_t)MROWS * 3 * DD * 2;
  short* vt  = (short*)ws; ws += (size_t)24 * 64 * TT * 2;
  short* ybf = (short*)ws; ws += (size_t)MROWS * DD * 2;
  short* ffb = (short*)ws; ws += (size_t)MROWS * 4 * DD * 2;

  if (bf16w) {
    cvt_k<<<dim3(4096), 256, 0, stream>>>(wqkv, wqkv_h, E_WQKV / 4);
    cvt_k<<<dim3(4096), 256, 0, stream>>>(wproj, wprj_h, E_WPRJ / 4);
    cvt_k<<<dim3(4096), 256, 0, stream>>>(w1, w1_h, E_W1 / 4);
    cvt_k<<<dim3(4096), 256, 0, stream>>>(w2, w2_h, E_W2 / 4);
    cvt_k<<<dim3(4096), 256, 0, stream>>>(tok, tok_h, E_TOK / 4);
    run_model<short>(idx, tok, pos, wqkv_h, bqkv, wprj_h, bproj,
                     ln1g, ln1b, ln2g, ln2b, w1_h, b1, w2_h, b2, lnfg, lnfb, tok_h,
                     xa, xb, hbf, qkv, vt, ybf, ffb, out, stream);
  } else {
    run_model<float>(idx, tok, pos, wqkv, bqkv, wproj, bproj,
                     ln1g, ln1b, ln2g, ln2b, w1, b1, w2, b2, lnfg, lnfb, tok,
                     xa, xb, hbf, qkv, vt, ybf, ffb, out, stream);
  }
}